// Round 10
// baseline (422.115 us; speedup 1.0000x reference)
//
#include <hip/hip_runtime.h>
#include <hip/hip_bf16.h>
#include <math.h>

#define FLn 96
#define SEG 288      // 3*FL
#define EPRE_DIM 192 // 2*FL
#define EPS_BN 1e-5f

typedef __attribute__((ext_vector_type(8))) short short8;
typedef __attribute__((ext_vector_type(4))) float floatx4;
typedef float v2f __attribute__((ext_vector_type(2)));

__device__ __forceinline__ float lrelu(float v) { return fmaxf(v, 0.1f * v); }
__device__ __forceinline__ short f2bf(float f) {
  __hip_bfloat16 h = __float2bfloat16(f);
  return *reinterpret_cast<short*>(&h);
}

// ---------------- K1: wave-per-(sample,half) + folded weight swizzle --------
// LDS slice layout (floats, per wave). Regions overlay in time:
//   phase1: c_in 0..287, st1 288..575, APP 576..673, ANP 674..771,
//           XPP 772..869, XNP 870..967, BERT 968..1063, WKER 1064..1072
//   phase2: ABF 0..383 (over c_in/st1-lo), BBF 384..767 (over st1-hi/APP/ANP)
//   phase3: RP 0..1631 (over everything; all dead)
#define O_CIN 0
#define O_ST1 288
#define O_APP 576
#define O_ANP 674
#define O_XPP 772
#define O_XNP 870
#define O_BERT 968
#define O_WKER 1064
#define O_ABF 0
#define O_BBF 384
#define O_RP 0
#define SLICE 1664   // 6.5 KB/wave -> 26 KB/block -> 6 blocks/CU

__global__ __launch_bounds__(256, 6) void k1_persample(
    const float* __restrict__ x,
    const float* __restrict__ cw1, const float* __restrict__ cb1,
    const float* __restrict__ cw2, const float* __restrict__ cb2,
    const float* __restrict__ cw3, const float* __restrict__ cb3,
    const float* __restrict__ cw4, const float* __restrict__ cb4,
    const float* __restrict__ cw5, const float* __restrict__ cb5,
    const float* __restrict__ cw6, const float* __restrict__ cb6,
    const float* __restrict__ deW, const float* __restrict__ deb,
    const float* __restrict__ rsW, const float* __restrict__ clW1,
    short* __restrict__ wB2s, short* __restrict__ wB3s,
    short* __restrict__ epre_s) {
  __shared__ float sl[4 * SLICE]; // 26 KB
  const int tid = threadIdx.x;
  const int wave = tid >> 6;
  const int lane = tid & 63;
  const int quad = lane >> 4;
  const int l16 = lane & 15;
  const int unit = blockIdx.x * 4 + wave;
  float* S = sl + wave * SLICE;
  short* Ssh = (short*)S;
  const float* xrow = x + (size_t)(unit >> 1) * 576 + (unit & 1) * 288;

  // ---- folded k0: swizzle-cast weights into MFMA-fragment order (<=1 el/thr)
  {
    int d = blockIdx.x * 256 + tid;
    if (d < 18 * 6 * 512) {
      int j = d & 7, ln = (d >> 3) & 63, t = d >> 9;
      int kf = t % 6, nf = t / 6;
      int n = nf * 16 + (ln & 15);
      int k = kf * 32 + (ln >> 4) * 8 + j;
      wB2s[d] = f2bf(rsW[n * 192 + k]);
    }
    if (d < 18 * 18 * 512) {
      int j = d & 7, ln = (d >> 3) & 63, t = d >> 9;
      int kf = t % 18, nt = t / 18;
      int n = nt * 16 + (ln & 15);
      int k = kf * 32 + (ln >> 4) * 8 + j;
      wB3s[d] = f2bf(clW1[n * 576 + k]);
    }
  }

  const float a0w0 = cw1[0], a0w1 = cw1[1], a0w2 = cw1[2], a0b = cb1[0];
  const float a1w0 = cw2[0], a1w1 = cw2[1], a1w2 = cw2[2], a1b = cb2[0];
  const float a2w0 = cw3[0], a2w1 = cw3[1], a2w2 = cw3[2], a2b = cb3[0];
  const float b0w0 = cw4[0], b0w1 = cw4[1], b0w2 = cw4[2], b0b = cb4[0];
  const float b1w0 = cw5[0], b1w1 = cw5[1], b1w2 = cw5[2], b1b = cb5[0];
  const float b2w0 = cw6[0], b2w1 = cw6[1], b2w2 = cw6[2], b2b = cb6[0];

  for (int t4 = lane; t4 < 72; t4 += 64)
    *(float4*)&S[O_CIN + 4 * t4] = ((const float4*)xrow)[t4];
  if (lane < 8) S[576 + 98 * (lane >> 1) + (lane & 1) * 97] = 0.f;

  // stage-1 convs
  for (int t = lane; t < SEG; t += 64) {
    bool g1 = t >= 96, g2 = t >= 192;
    float wa = g2 ? a2w0 : (g1 ? a1w0 : a0w0);
    float wb = g2 ? a2w1 : (g1 ? a1w1 : a0w1);
    float wc = g2 ? a2w2 : (g1 ? a1w2 : a0w2);
    float bb = g2 ? a2b  : (g1 ? a1b  : a0b);
    int p = t - (g2 ? 192 : (g1 ? 96 : 0));
    float l = p > 0 ? S[O_CIN + t - 1] : 0.f;
    float m = S[O_CIN + t];
    float r = p < FLn - 1 ? S[O_CIN + t + 1] : 0.f;
    S[O_ST1 + t] = lrelu(fmaf(wa, l, fmaf(wb, m, fmaf(wc, r, bb))));
  }
  // stage-2 convs -> aPp/aNp, xpP/xnP, bert
  for (int t = lane; t < SEG; t += 64) {
    bool g1 = t >= 96, g2 = t >= 192;
    float wa = g2 ? b2w0 : (g1 ? b1w0 : b0w0);
    float wb = g2 ? b2w1 : (g1 ? b1w1 : b0w1);
    float wc = g2 ? b2w2 : (g1 ? b1w2 : b0w2);
    float bb = g2 ? b2b  : (g1 ? b1b  : b0b);
    int p = t - (g2 ? 192 : (g1 ? 96 : 0));
    float l = p > 0 ? S[O_ST1 + t - 1] : 0.f;
    float m = S[O_ST1 + t];
    float r = p < FLn - 1 ? S[O_ST1 + t + 1] : 0.f;
    float v = lrelu(fmaf(wa, l, fmaf(wb, m, fmaf(wc, r, bb))));
    if (!g1) {
      S[O_APP + 1 + p] = fmaxf(v, 0.1f * v);
      S[O_ANP + 1 + p] = fminf(v, 0.1f * v);
    } else if (!g2) {
      S[O_XPP + 1 + p] = fmaxf(v, 0.f);
      S[O_XNP + 1 + p] = fminf(v, 0.f);
    } else {
      S[O_BERT + p] = v;
    }
  }
  // per-sample 3x3 kernel: wker = lrelu(bert @ deW.T + deb)
  if (quad < 3) {
    float bv[6];
#pragma unroll
    for (int k = 0; k < 6; ++k) bv[k] = S[O_BERT + l16 + 16 * k];
#pragma unroll
    for (int oi = 0; oi < 3; ++oi) {
      int o = quad * 3 + oi;
      float p = 0.f;
#pragma unroll
      for (int k = 0; k < 6; ++k) p = fmaf(bv[k], deW[o * 96 + l16 + 16 * k], p);
      p += __shfl_xor(p, 1, 16);
      p += __shfl_xor(p, 2, 16);
      p += __shfl_xor(p, 4, 16);
      p += __shfl_xor(p, 8, 16);
      if (l16 == 0) S[O_WKER + o] = lrelu(p + deb[o]);
    }
  }

  // ---- A matrix build FIRST (reads APP/ANP, writes ABF over c_in/st1-lo) ---
  for (int m = lane; m < 96; m += 64) {
    short8 a;
    a[0] = f2bf(S[O_APP + m]);
    a[1] = f2bf(S[O_APP + m + 1]);
    a[2] = f2bf(S[O_APP + m + 2]);
    a[3] = f2bf(S[O_ANP + m]);
    a[4] = f2bf(S[O_ANP + m + 1]);
    a[5] = f2bf(S[O_ANP + m + 2]);
    a[6] = 0; a[7] = 0;
    *(short8*)&Ssh[2 * O_ABF + m * 8] = a;
  }
  // ---- B matrix build: 0.25-scaled (4-quad replication sums back to 1x) ----
  float w9[9];
#pragma unroll
  for (int q = 0; q < 9; ++q) w9[q] = 0.25f * S[O_WKER + q];
  for (int t = lane; t < 96; t += 64) {
    float xp0 = S[O_XPP + t], xp1 = S[O_XPP + t + 1], xp2 = S[O_XPP + t + 2];
    float xn0 = S[O_XNP + t], xn1 = S[O_XNP + t + 1], xn2 = S[O_XNP + t + 2];
    short8 b;
#pragma unroll
    for (int d = 0; d < 3; ++d) {
      float cp = fmaf(w9[3 * d], xp0, fmaf(w9[3 * d + 1], xp1, w9[3 * d + 2] * xp2));
      float cn = fmaf(w9[3 * d], xn0, fmaf(w9[3 * d + 1], xn1, w9[3 * d + 2] * xn2));
      b[d] = f2bf(cp);
      b[3 + d] = f2bf(cn);
    }
    b[6] = 0; b[7] = 0;
    *(short8*)&Ssh[2 * O_BBF + t * 8] = b;
  }

  // A-fragments: plain broadcast reads (all quads same address; no masking)
  short8 aF[6];
#pragma unroll
  for (int mt = 0; mt < 6; ++mt)
    aF[mt] = *(const short8*)&Ssh[2 * O_ABF + (mt * 16 + l16) * 8];

  v2f rp2[6][2];
#pragma unroll
  for (int mt = 0; mt < 6; ++mt) {
    rp2[mt][0] = (v2f){0.f, 0.f};
    rp2[mt][1] = (v2f){0.f, 0.f};
  }
  float cs[6];

#pragma unroll
  for (int s = 0; s < 6; ++s) {
    short8 bF = *(const short8*)&Ssh[2 * O_BBF + (s * 16 + l16) * 8];
    floatx4 accv[6];
#pragma unroll
    for (int mt = 0; mt < 6; ++mt)
      accv[mt] = __builtin_amdgcn_mfma_f32_16x16x32_bf16(
          aF[mt], bF, (floatx4){0.f, 0.f, 0.f, 0.f}, 0, 0, 0);
    v2f csl = (v2f){0.f, 0.f};
#pragma unroll
    for (int mt = 0; mt < 6; ++mt) {
      v2f lo = (v2f){accv[mt][0], accv[mt][1]};
      v2f hi = (v2f){accv[mt][2], accv[mt][3]};
      v2f tl = 0.1f * lo;
      v2f th = 0.1f * hi;
      v2f fl, fh;
      fl.x = fmaxf(lo.x, tl.x); fl.y = fmaxf(lo.y, tl.y);
      fh.x = fmaxf(hi.x, th.x); fh.y = fmaxf(hi.y, th.y);
      rp2[mt][0] += fl;
      rp2[mt][1] += fh;
      csl += fl + fh;
    }
    cs[s] = csl.x + csl.y;
  }

  // row partials -> LDS (RP overlays everything; all prior regions dead)
#pragma unroll
  for (int mt = 0; mt < 6; ++mt)
    *(float4*)&S[O_RP + (quad * 6 + mt) * 68 + l16 * 4] =
        make_float4(rp2[mt][0].x, rp2[mt][0].y, rp2[mt][1].x, rp2[mt][1].y);

  // ---- swizzled epre writes: dst = (g*6+kf)*512 + (q*16 + (unit&15))*8 + j
  const int g = unit >> 4;
  const int u15 = unit & 15;
  short* eb = epre_s + (size_t)g * 6 * 512;
  // row means: value at kidx = i (0..95)
  for (int i = lane; i < 96; i += 64) {
    int gg = ((i >> 2) & 3) * 6 + (i >> 4);
    int r = i & 3;
    float s = 0.f;
#pragma unroll
    for (int l = 0; l < 16; ++l) s += S[O_RP + gg * 68 + l * 4 + r];
    int kf = i >> 5, rem = i & 31, q = rem >> 3, j = rem & 7;
    eb[kf * 512 + (q * 16 + u15) * 8 + j] = f2bf(s * (1.f / FLn));
  }
  // col means: value at kidx = 96 + s*16 + l16
#pragma unroll
  for (int s = 0; s < 6; ++s) {
    float v = cs[s];
    v += __shfl_xor(v, 16, 64);
    v += __shfl_xor(v, 32, 64);
    if (quad == 0) {
      int kidx = 96 + s * 16 + l16;
      int kf = kidx >> 5, rem = kidx & 31, q = rem >> 3, j = rem & 7;
      eb[kf * 512 + (q * 16 + u15) * 8 + j] = f2bf(v * (1.f / FLn));
    }
  }
}

// ---------------- K6: fused tail, fragment-contiguous loads (R9 proven) -----
__global__ __launch_bounds__(512) void k6_fused_tail(
    const short* __restrict__ epre_s, const short* __restrict__ wB2s,
    const short* __restrict__ wB3s, const float* __restrict__ x,
    const float* __restrict__ rsb, const float* __restrict__ rsg,
    const float* __restrict__ rsbe, const float* __restrict__ rsm,
    const float* __restrict__ rsv,
    const float* __restrict__ clb1, const float* __restrict__ clg,
    const float* __restrict__ clbe, const float* __restrict__ clm,
    const float* __restrict__ clv,
    const float* __restrict__ clW2, const float* __restrict__ clb2,
    float* __restrict__ out) {
  __shared__ short ceT[16 * 584]; // 18.7 KB
  __shared__ float scr[8 * 32];
  const int tid = threadIdx.x;
  const int w = tid >> 6;
  const int lane = tid & 63;
  const int quad = lane >> 4;
  const int l16 = lane & 15;
  const int s0 = blockIdx.x * 16;

  // ---- phase A ----
  const int mt = w & 1;
  const int ng = w >> 1;  // 0..3
  short8 aF[6];
  {
    const short* arow = epre_s + (size_t)(blockIdx.x * 2 + mt) * 6 * 512 + lane * 8;
#pragma unroll
    for (int kf = 0; kf < 6; ++kf) aF[kf] = *(const short8*)(arow + kf * 512);
  }

  for (int nf = ng; nf < 18; nf += 4) {
    const short* brow = wB2s + (size_t)nf * 6 * 512 + lane * 8;
    floatx4 acc = (floatx4){0.f, 0.f, 0.f, 0.f};
#pragma unroll
    for (int kf = 0; kf < 6; ++kf) {
      short8 bF = *(const short8*)(brow + kf * 512);
      acc = __builtin_amdgcn_mfma_f32_16x16x32_bf16(aF[kf], bF, acc, 0, 0, 0);
    }
    const int n = nf * 16 + l16;
    const float sc = rsg[n] * rsqrtf(rsv[n] + EPS_BN);
    const float vb = rsb[n], mu = rsm[n], vbe = rsbe[n];
#pragma unroll
    for (int r = 0; r < 4; ++r) {
      int um = mt * 16 + quad * 4 + r;   // unit-in-block 0..31
      int trow = um >> 1;                // sample 0..15
      int cc = (um & 1) * 288 + n;       // col 0..575
      float y = acc[r] + vb;
      float o = (y - mu) * sc + vbe;
      float e = lrelu(o) + x[(size_t)(s0 + trow) * 576 + cc];
      ceT[trow * 584 + cc] = f2bf(e);
    }
  }
  __syncthreads();

  // ---- phase B (+ cl2 fold) ----
  float p0[4], p1[4];
#pragma unroll
  for (int r = 0; r < 4; ++r) { p0[r] = 0.f; p1[r] = 0.f; }

  for (int nt = w; nt < 18; nt += 8) {
    const short* brow = wB3s + (size_t)nt * 18 * 512 + lane * 8;
    floatx4 acc = (floatx4){0.f, 0.f, 0.f, 0.f};
#pragma unroll
    for (int kf = 0; kf < 18; ++kf) {
      short8 cF = *(const short8*)&ceT[l16 * 584 + kf * 32 + quad * 8];
      short8 bF = *(const short8*)(brow + kf * 512);
      acc = __builtin_amdgcn_mfma_f32_16x16x32_bf16(cF, bF, acc, 0, 0, 0);
    }
    const int n = nt * 16 + l16;
    const float sc = clg[n] * rsqrtf(clv[n] + EPS_BN);
    const float vb = clb1[n], mu = clm[n], vbe = clbe[n];
    const float w2a = clW2[n], w2b = clW2[288 + n];
#pragma unroll
    for (int r = 0; r < 4; ++r) {
      float y = acc[r] + vb;
      float hh = fmaxf((y - mu) * sc + vbe, 0.f);
      p0[r] = fmaf(hh, w2a, p0[r]);
      p1[r] = fmaf(hh, w2b, p1[r]);
    }
  }
#pragma unroll
  for (int r = 0; r < 4; ++r) {
#pragma unroll
    for (int off = 1; off < 16; off <<= 1) {
      p0[r] += __shfl_xor(p0[r], off, 64);
      p1[r] += __shfl_xor(p1[r], off, 64);
    }
  }
  if (l16 == 0) {
#pragma unroll
    for (int r = 0; r < 4; ++r) {
      scr[w * 32 + (quad * 4 + r) * 2 + 0] = p0[r];
      scr[w * 32 + (quad * 4 + r) * 2 + 1] = p1[r];
    }
  }
  __syncthreads();
  if (tid < 32) {
    int row = tid >> 1, o = tid & 1;
    float s = 0.f;
#pragma unroll
    for (int g = 0; g < 8; ++g) s += scr[g * 32 + row * 2 + o];
    out[(size_t)(s0 + row) * 2 + o] = s + clb2[o];
  }
}

extern "C" void kernel_launch(void* const* d_in, const int* in_sizes, int n_in,
                              void* d_out, int out_size, void* d_ws, size_t ws_size,
                              hipStream_t stream) {
  const float* x   = (const float*)d_in[0];
  const float* cw1 = (const float*)d_in[1];  const float* cb1 = (const float*)d_in[2];
  const float* cw2 = (const float*)d_in[3];  const float* cb2 = (const float*)d_in[4];
  const float* cw3 = (const float*)d_in[5];  const float* cb3 = (const float*)d_in[6];
  const float* cw4 = (const float*)d_in[7];  const float* cb4 = (const float*)d_in[8];
  const float* cw5 = (const float*)d_in[9];  const float* cb5 = (const float*)d_in[10];
  const float* cw6 = (const float*)d_in[11]; const float* cb6 = (const float*)d_in[12];
  const float* deW = (const float*)d_in[13]; const float* deb = (const float*)d_in[14];
  const float* rsW = (const float*)d_in[15]; const float* rsb = (const float*)d_in[16];
  const float* rsg = (const float*)d_in[17]; const float* rsbe = (const float*)d_in[18];
  const float* rsm = (const float*)d_in[19]; const float* rsv = (const float*)d_in[20];
  const float* clW1 = (const float*)d_in[21]; const float* clb1 = (const float*)d_in[22];
  const float* clg = (const float*)d_in[23]; const float* clbe = (const float*)d_in[24];
  const float* clm = (const float*)d_in[25]; const float* clv = (const float*)d_in[26];
  const float* clW2 = (const float*)d_in[27]; const float* clb2 = (const float*)d_in[28];

  short* ws     = (short*)d_ws;
  short* epre_s = ws;                         // 16384*192 bf16 (fragment order)
  short* wB2s   = ws + 16384 * 192;           // 18*6*512 bf16
  short* wB3s   = wB2s + 18 * 6 * 512;        // 18*18*512 bf16

  hipLaunchKernelGGL(k1_persample, dim3(4096), dim3(256), 0, stream, x,
                     cw1, cb1, cw2, cb2, cw3, cb3, cw4, cb4, cw5, cb5, cw6, cb6,
                     deW, deb, rsW, clW1, wB2s, wB3s, epre_s);
  hipLaunchKernelGGL(k6_fused_tail, dim3(512), dim3(512), 0, stream,
                     epre_s, wB2s, wB3s, x,
                     rsb, rsg, rsbe, rsm, rsv,
                     clb1, clg, clbe, clm, clv,
                     clW2, clb2, (float*)d_out);
}

// Round 11
// 195.771 us; speedup vs baseline: 2.1562x; 2.1562x over previous
//
#include <hip/hip_runtime.h>
#include <hip/hip_bf16.h>
#include <math.h>

#define FLn 96
#define SEG 288      // 3*FL
#define EPRE_DIM 192 // 2*FL
#define EPS_BN 1e-5f

typedef __attribute__((ext_vector_type(8))) short short8;
typedef __attribute__((ext_vector_type(4))) float floatx4;
typedef float v2f __attribute__((ext_vector_type(2)));

__device__ __forceinline__ float lrelu(float v) { return fmaxf(v, 0.1f * v); }
__device__ __forceinline__ short f2bf(float f) {
  __hip_bfloat16 h = __float2bfloat16(f);
  return *reinterpret_cast<short*>(&h);
}

// ---------------- K1: wave-per-(sample,half) + folded weight swizzle --------
// NOTE: no min-waves in __launch_bounds__ — R10's (256,6) forced VGPR=40 and
// ~1.1 GB/dispatch of scratch spill traffic (WRITE_SIZE 747 MB). Allocator
// must stay free; occupancy is LDS-bound at 6 blocks/CU (26 KB) anyway.
#define O_CIN 0
#define O_ST1 288
#define O_APP 576
#define O_ANP 674
#define O_XPP 772
#define O_XNP 870
#define O_BERT 968
#define O_WKER 1064
#define O_ABF 0
#define O_BBF 384
#define O_RP 0
#define SLICE 1664   // 6.5 KB/wave -> 26 KB/block -> 6 blocks/CU

__global__ __launch_bounds__(256) void k1_persample(
    const float* __restrict__ x,
    const float* __restrict__ cw1, const float* __restrict__ cb1,
    const float* __restrict__ cw2, const float* __restrict__ cb2,
    const float* __restrict__ cw3, const float* __restrict__ cb3,
    const float* __restrict__ cw4, const float* __restrict__ cb4,
    const float* __restrict__ cw5, const float* __restrict__ cb5,
    const float* __restrict__ cw6, const float* __restrict__ cb6,
    const float* __restrict__ deW, const float* __restrict__ deb,
    const float* __restrict__ rsW, const float* __restrict__ clW1,
    short* __restrict__ wB2s, short* __restrict__ wB3s,
    short* __restrict__ epre_s) {
  __shared__ float sl[4 * SLICE]; // 26 KB
  const int tid = threadIdx.x;
  const int wave = tid >> 6;
  const int lane = tid & 63;
  const int quad = lane >> 4;
  const int l16 = lane & 15;
  const int unit = blockIdx.x * 4 + wave;
  float* S = sl + wave * SLICE;
  short* Ssh = (short*)S;
  const float* xrow = x + (size_t)(unit >> 1) * 576 + (unit & 1) * 288;

  // ---- folded k0: swizzle-cast weights into MFMA-fragment order (<=1 el/thr)
  {
    int d = blockIdx.x * 256 + tid;
    if (d < 18 * 6 * 512) {
      int j = d & 7, ln = (d >> 3) & 63, t = d >> 9;
      int kf = t % 6, nf = t / 6;
      int n = nf * 16 + (ln & 15);
      int k = kf * 32 + (ln >> 4) * 8 + j;
      wB2s[d] = f2bf(rsW[n * 192 + k]);
    }
    if (d < 18 * 18 * 512) {
      int j = d & 7, ln = (d >> 3) & 63, t = d >> 9;
      int kf = t % 18, nt = t / 18;
      int n = nt * 16 + (ln & 15);
      int k = kf * 32 + (ln >> 4) * 8 + j;
      wB3s[d] = f2bf(clW1[n * 576 + k]);
    }
  }

  const float a0w0 = cw1[0], a0w1 = cw1[1], a0w2 = cw1[2], a0b = cb1[0];
  const float a1w0 = cw2[0], a1w1 = cw2[1], a1w2 = cw2[2], a1b = cb2[0];
  const float a2w0 = cw3[0], a2w1 = cw3[1], a2w2 = cw3[2], a2b = cb3[0];
  const float b0w0 = cw4[0], b0w1 = cw4[1], b0w2 = cw4[2], b0b = cb4[0];
  const float b1w0 = cw5[0], b1w1 = cw5[1], b1w2 = cw5[2], b1b = cb5[0];
  const float b2w0 = cw6[0], b2w1 = cw6[1], b2w2 = cw6[2], b2b = cb6[0];

  for (int t4 = lane; t4 < 72; t4 += 64)
    *(float4*)&S[O_CIN + 4 * t4] = ((const float4*)xrow)[t4];
  if (lane < 8) S[576 + 98 * (lane >> 1) + (lane & 1) * 97] = 0.f;

  // stage-1 convs
  for (int t = lane; t < SEG; t += 64) {
    bool g1 = t >= 96, g2 = t >= 192;
    float wa = g2 ? a2w0 : (g1 ? a1w0 : a0w0);
    float wb = g2 ? a2w1 : (g1 ? a1w1 : a0w1);
    float wc = g2 ? a2w2 : (g1 ? a1w2 : a0w2);
    float bb = g2 ? a2b  : (g1 ? a1b  : a0b);
    int p = t - (g2 ? 192 : (g1 ? 96 : 0));
    float l = p > 0 ? S[O_CIN + t - 1] : 0.f;
    float m = S[O_CIN + t];
    float r = p < FLn - 1 ? S[O_CIN + t + 1] : 0.f;
    S[O_ST1 + t] = lrelu(fmaf(wa, l, fmaf(wb, m, fmaf(wc, r, bb))));
  }
  // stage-2 convs -> aPp/aNp, xpP/xnP, bert
  for (int t = lane; t < SEG; t += 64) {
    bool g1 = t >= 96, g2 = t >= 192;
    float wa = g2 ? b2w0 : (g1 ? b1w0 : b0w0);
    float wb = g2 ? b2w1 : (g1 ? b1w1 : b0w1);
    float wc = g2 ? b2w2 : (g1 ? b1w2 : b0w2);
    float bb = g2 ? b2b  : (g1 ? b1b  : b0b);
    int p = t - (g2 ? 192 : (g1 ? 96 : 0));
    float l = p > 0 ? S[O_ST1 + t - 1] : 0.f;
    float m = S[O_ST1 + t];
    float r = p < FLn - 1 ? S[O_ST1 + t + 1] : 0.f;
    float v = lrelu(fmaf(wa, l, fmaf(wb, m, fmaf(wc, r, bb))));
    if (!g1) {
      S[O_APP + 1 + p] = fmaxf(v, 0.1f * v);
      S[O_ANP + 1 + p] = fminf(v, 0.1f * v);
    } else if (!g2) {
      S[O_XPP + 1 + p] = fmaxf(v, 0.f);
      S[O_XNP + 1 + p] = fminf(v, 0.f);
    } else {
      S[O_BERT + p] = v;
    }
  }
  // per-sample 3x3 kernel: wker = lrelu(bert @ deW.T + deb)
  if (quad < 3) {
    float bv[6];
#pragma unroll
    for (int k = 0; k < 6; ++k) bv[k] = S[O_BERT + l16 + 16 * k];
#pragma unroll
    for (int oi = 0; oi < 3; ++oi) {
      int o = quad * 3 + oi;
      float p = 0.f;
#pragma unroll
      for (int k = 0; k < 6; ++k) p = fmaf(bv[k], deW[o * 96 + l16 + 16 * k], p);
      p += __shfl_xor(p, 1, 16);
      p += __shfl_xor(p, 2, 16);
      p += __shfl_xor(p, 4, 16);
      p += __shfl_xor(p, 8, 16);
      if (l16 == 0) S[O_WKER + o] = lrelu(p + deb[o]);
    }
  }

  // ---- A matrix build FIRST (reads APP/ANP, writes ABF over c_in/st1-lo) ---
  for (int m = lane; m < 96; m += 64) {
    short8 a;
    a[0] = f2bf(S[O_APP + m]);
    a[1] = f2bf(S[O_APP + m + 1]);
    a[2] = f2bf(S[O_APP + m + 2]);
    a[3] = f2bf(S[O_ANP + m]);
    a[4] = f2bf(S[O_ANP + m + 1]);
    a[5] = f2bf(S[O_ANP + m + 2]);
    a[6] = 0; a[7] = 0;
    *(short8*)&Ssh[2 * O_ABF + m * 8] = a;
  }
  // ---- B matrix build: 0.25-scaled (4-quad replication sums back to 1x) ----
  float w9[9];
#pragma unroll
  for (int q = 0; q < 9; ++q) w9[q] = 0.25f * S[O_WKER + q];
  for (int t = lane; t < 96; t += 64) {
    float xp0 = S[O_XPP + t], xp1 = S[O_XPP + t + 1], xp2 = S[O_XPP + t + 2];
    float xn0 = S[O_XNP + t], xn1 = S[O_XNP + t + 1], xn2 = S[O_XNP + t + 2];
    short8 b;
#pragma unroll
    for (int d = 0; d < 3; ++d) {
      float cp = fmaf(w9[3 * d], xp0, fmaf(w9[3 * d + 1], xp1, w9[3 * d + 2] * xp2));
      float cn = fmaf(w9[3 * d], xn0, fmaf(w9[3 * d + 1], xn1, w9[3 * d + 2] * xn2));
      b[d] = f2bf(cp);
      b[3 + d] = f2bf(cn);
    }
    b[6] = 0; b[7] = 0;
    *(short8*)&Ssh[2 * O_BBF + t * 8] = b;
  }

  // A-fragments: plain broadcast reads (all quads same address; no masking)
  short8 aF[6];
#pragma unroll
  for (int mt = 0; mt < 6; ++mt)
    aF[mt] = *(const short8*)&Ssh[2 * O_ABF + (mt * 16 + l16) * 8];

  v2f rp2[6][2];
#pragma unroll
  for (int mt = 0; mt < 6; ++mt) {
    rp2[mt][0] = (v2f){0.f, 0.f};
    rp2[mt][1] = (v2f){0.f, 0.f};
  }
  float cs[6];

#pragma unroll
  for (int s = 0; s < 6; ++s) {
    short8 bF = *(const short8*)&Ssh[2 * O_BBF + (s * 16 + l16) * 8];
    floatx4 accv[6];
#pragma unroll
    for (int mt = 0; mt < 6; ++mt)
      accv[mt] = __builtin_amdgcn_mfma_f32_16x16x32_bf16(
          aF[mt], bF, (floatx4){0.f, 0.f, 0.f, 0.f}, 0, 0, 0);
    v2f csl = (v2f){0.f, 0.f};
#pragma unroll
    for (int mt = 0; mt < 6; ++mt) {
      v2f lo = (v2f){accv[mt][0], accv[mt][1]};
      v2f hi = (v2f){accv[mt][2], accv[mt][3]};
      v2f tl = 0.1f * lo;
      v2f th = 0.1f * hi;
      v2f fl, fh;
      fl.x = fmaxf(lo.x, tl.x); fl.y = fmaxf(lo.y, tl.y);
      fh.x = fmaxf(hi.x, th.x); fh.y = fmaxf(hi.y, th.y);
      rp2[mt][0] += fl;
      rp2[mt][1] += fh;
      csl += fl + fh;
    }
    cs[s] = csl.x + csl.y;
  }

  // row partials -> LDS (RP overlays everything; all prior regions dead)
#pragma unroll
  for (int mt = 0; mt < 6; ++mt)
    *(float4*)&S[O_RP + (quad * 6 + mt) * 68 + l16 * 4] =
        make_float4(rp2[mt][0].x, rp2[mt][0].y, rp2[mt][1].x, rp2[mt][1].y);

  // ---- swizzled epre writes: dst = (g*6+kf)*512 + (q*16 + (unit&15))*8 + j
  const int g = unit >> 4;
  const int u15 = unit & 15;
  short* eb = epre_s + (size_t)g * 6 * 512;
  // row means: value at kidx = i (0..95)
  for (int i = lane; i < 96; i += 64) {
    int gg = ((i >> 2) & 3) * 6 + (i >> 4);
    int r = i & 3;
    float s = 0.f;
#pragma unroll
    for (int l = 0; l < 16; ++l) s += S[O_RP + gg * 68 + l * 4 + r];
    int kf = i >> 5, rem = i & 31, q = rem >> 3, j = rem & 7;
    eb[kf * 512 + (q * 16 + u15) * 8 + j] = f2bf(s * (1.f / FLn));
  }
  // col means: value at kidx = 96 + s*16 + l16
#pragma unroll
  for (int s = 0; s < 6; ++s) {
    float v = cs[s];
    v += __shfl_xor(v, 16, 64);
    v += __shfl_xor(v, 32, 64);
    if (quad == 0) {
      int kidx = 96 + s * 16 + l16;
      int kf = kidx >> 5, rem = kidx & 31, q = rem >> 3, j = rem & 7;
      eb[kf * 512 + (q * 16 + u15) * 8 + j] = f2bf(v * (1.f / FLn));
    }
  }
}

// ---------------- K6: fused tail, fragment-contiguous loads (R9 proven) -----
__global__ __launch_bounds__(512) void k6_fused_tail(
    const short* __restrict__ epre_s, const short* __restrict__ wB2s,
    const short* __restrict__ wB3s, const float* __restrict__ x,
    const float* __restrict__ rsb, const float* __restrict__ rsg,
    const float* __restrict__ rsbe, const float* __restrict__ rsm,
    const float* __restrict__ rsv,
    const float* __restrict__ clb1, const float* __restrict__ clg,
    const float* __restrict__ clbe, const float* __restrict__ clm,
    const float* __restrict__ clv,
    const float* __restrict__ clW2, const float* __restrict__ clb2,
    float* __restrict__ out) {
  __shared__ short ceT[16 * 584]; // 18.7 KB
  __shared__ float scr[8 * 32];
  const int tid = threadIdx.x;
  const int w = tid >> 6;
  const int lane = tid & 63;
  const int quad = lane >> 4;
  const int l16 = lane & 15;
  const int s0 = blockIdx.x * 16;

  // ---- phase A ----
  const int mt = w & 1;
  const int ng = w >> 1;  // 0..3
  short8 aF[6];
  {
    const short* arow = epre_s + (size_t)(blockIdx.x * 2 + mt) * 6 * 512 + lane * 8;
#pragma unroll
    for (int kf = 0; kf < 6; ++kf) aF[kf] = *(const short8*)(arow + kf * 512);
  }

  for (int nf = ng; nf < 18; nf += 4) {
    const short* brow = wB2s + (size_t)nf * 6 * 512 + lane * 8;
    floatx4 acc = (floatx4){0.f, 0.f, 0.f, 0.f};
#pragma unroll
    for (int kf = 0; kf < 6; ++kf) {
      short8 bF = *(const short8*)(brow + kf * 512);
      acc = __builtin_amdgcn_mfma_f32_16x16x32_bf16(aF[kf], bF, acc, 0, 0, 0);
    }
    const int n = nf * 16 + l16;
    const float sc = rsg[n] * rsqrtf(rsv[n] + EPS_BN);
    const float vb = rsb[n], mu = rsm[n], vbe = rsbe[n];
#pragma unroll
    for (int r = 0; r < 4; ++r) {
      int um = mt * 16 + quad * 4 + r;   // unit-in-block 0..31
      int trow = um >> 1;                // sample 0..15
      int cc = (um & 1) * 288 + n;       // col 0..575
      float y = acc[r] + vb;
      float o = (y - mu) * sc + vbe;
      float e = lrelu(o) + x[(size_t)(s0 + trow) * 576 + cc];
      ceT[trow * 584 + cc] = f2bf(e);
    }
  }
  __syncthreads();

  // ---- phase B (+ cl2 fold) ----
  float p0[4], p1[4];
#pragma unroll
  for (int r = 0; r < 4; ++r) { p0[r] = 0.f; p1[r] = 0.f; }

  for (int nt = w; nt < 18; nt += 8) {
    const short* brow = wB3s + (size_t)nt * 18 * 512 + lane * 8;
    floatx4 acc = (floatx4){0.f, 0.f, 0.f, 0.f};
#pragma unroll
    for (int kf = 0; kf < 18; ++kf) {
      short8 cF = *(const short8*)&ceT[l16 * 584 + kf * 32 + quad * 8];
      short8 bF = *(const short8*)(brow + kf * 512);
      acc = __builtin_amdgcn_mfma_f32_16x16x32_bf16(cF, bF, acc, 0, 0, 0);
    }
    const int n = nt * 16 + l16;
    const float sc = clg[n] * rsqrtf(clv[n] + EPS_BN);
    const float vb = clb1[n], mu = clm[n], vbe = clbe[n];
    const float w2a = clW2[n], w2b = clW2[288 + n];
#pragma unroll
    for (int r = 0; r < 4; ++r) {
      float y = acc[r] + vb;
      float hh = fmaxf((y - mu) * sc + vbe, 0.f);
      p0[r] = fmaf(hh, w2a, p0[r]);
      p1[r] = fmaf(hh, w2b, p1[r]);
    }
  }
#pragma unroll
  for (int r = 0; r < 4; ++r) {
#pragma unroll
    for (int off = 1; off < 16; off <<= 1) {
      p0[r] += __shfl_xor(p0[r], off, 64);
      p1[r] += __shfl_xor(p1[r], off, 64);
    }
  }
  if (l16 == 0) {
#pragma unroll
    for (int r = 0; r < 4; ++r) {
      scr[w * 32 + (quad * 4 + r) * 2 + 0] = p0[r];
      scr[w * 32 + (quad * 4 + r) * 2 + 1] = p1[r];
    }
  }
  __syncthreads();
  if (tid < 32) {
    int row = tid >> 1, o = tid & 1;
    float s = 0.f;
#pragma unroll
    for (int g = 0; g < 8; ++g) s += scr[g * 32 + row * 2 + o];
    out[(size_t)(s0 + row) * 2 + o] = s + clb2[o];
  }
}

extern "C" void kernel_launch(void* const* d_in, const int* in_sizes, int n_in,
                              void* d_out, int out_size, void* d_ws, size_t ws_size,
                              hipStream_t stream) {
  const float* x   = (const float*)d_in[0];
  const float* cw1 = (const float*)d_in[1];  const float* cb1 = (const float*)d_in[2];
  const float* cw2 = (const float*)d_in[3];  const float* cb2 = (const float*)d_in[4];
  const float* cw3 = (const float*)d_in[5];  const float* cb3 = (const float*)d_in[6];
  const float* cw4 = (const float*)d_in[7];  const float* cb4 = (const float*)d_in[8];
  const float* cw5 = (const float*)d_in[9];  const float* cb5 = (const float*)d_in[10];
  const float* cw6 = (const float*)d_in[11]; const float* cb6 = (const float*)d_in[12];
  const float* deW = (const float*)d_in[13]; const float* deb = (const float*)d_in[14];
  const float* rsW = (const float*)d_in[15]; const float* rsb = (const float*)d_in[16];
  const float* rsg = (const float*)d_in[17]; const float* rsbe = (const float*)d_in[18];
  const float* rsm = (const float*)d_in[19]; const float* rsv = (const float*)d_in[20];
  const float* clW1 = (const float*)d_in[21]; const float* clb1 = (const float*)d_in[22];
  const float* clg = (const float*)d_in[23]; const float* clbe = (const float*)d_in[24];
  const float* clm = (const float*)d_in[25]; const float* clv = (const float*)d_in[26];
  const float* clW2 = (const float*)d_in[27]; const float* clb2 = (const float*)d_in[28];

  short* ws     = (short*)d_ws;
  short* epre_s = ws;                         // 16384*192 bf16 (fragment order)
  short* wB2s   = ws + 16384 * 192;           // 18*6*512 bf16
  short* wB3s   = wB2s + 18 * 6 * 512;        // 18*18*512 bf16

  hipLaunchKernelGGL(k1_persample, dim3(4096), dim3(256), 0, stream, x,
                     cw1, cb1, cw2, cb2, cw3, cb3, cw4, cb4, cw5, cb5, cw6, cb6,
                     deW, deb, rsW, clW1, wB2s, wB3s, epre_s);
  hipLaunchKernelGGL(k6_fused_tail, dim3(512), dim3(512), 0, stream,
                     epre_s, wB2s, wB3s, x,
                     rsb, rsg, rsbe, rsm, rsv,
                     clb1, clg, clbe, clm, clv,
                     clW2, clb2, (float*)d_out);
}

// Round 12
// 191.288 us; speedup vs baseline: 2.2067x; 1.0234x over previous
//
#include <hip/hip_runtime.h>
#include <hip/hip_bf16.h>
#include <math.h>

#define FLn 96
#define SEG 288      // 3*FL
#define EPRE_DIM 192 // 2*FL
#define EPS_BN 1e-5f

typedef __attribute__((ext_vector_type(8))) short short8;
typedef __attribute__((ext_vector_type(4))) float floatx4;
typedef float v2f __attribute__((ext_vector_type(2)));

__device__ __forceinline__ float lrelu(float v) { return fmaxf(v, 0.1f * v); }
__device__ __forceinline__ short f2bf(float f) {
  __hip_bfloat16 h = __float2bfloat16(f);
  return *reinterpret_cast<short*>(&h);
}

// ---------------- K1: TWO waves per (sample,half) unit ----------------------
// Block = 128 threads = 1 unit. Serial stages split across the wave pair:
// conv loops stride-128; wker (wave0) || A-build (wave1); field splits by
// s-tiles (3 each) halving the epilogue; per-wave RP regions summed at read.
// NOTE: no min-waves in __launch_bounds__ (R10: (256,6) forced VGPR=40 ->
// 1.1 GB/dispatch scratch spill).
// LDS overlay (floats): phase1 CIN 0..287, ST1 288..575, APP 576..673,
// ANP 674..771, XPP 772..869, XNP 870..967, BERT 968..1063, WKER 1064..1072;
// phase2 ABF 0..383 (over CIN/ST1lo), BBF 384..767 (over ST1hi/APP/ANPlo);
// phase3 RP 0..3263 (two 1632 regions; everything dead).
#define O_CIN 0
#define O_ST1 288
#define O_APP 576
#define O_ANP 674
#define O_XPP 772
#define O_XNP 870
#define O_BERT 968
#define O_WKER 1064
#define O_ABF 0
#define O_BBF 384
#define O_RP 0
#define RPREG 1632
#define SLICE 3264   // 12.75 KB/block

__global__ __launch_bounds__(128) void k1_persample(
    const float* __restrict__ x,
    const float* __restrict__ cw1, const float* __restrict__ cb1,
    const float* __restrict__ cw2, const float* __restrict__ cb2,
    const float* __restrict__ cw3, const float* __restrict__ cb3,
    const float* __restrict__ cw4, const float* __restrict__ cb4,
    const float* __restrict__ cw5, const float* __restrict__ cb5,
    const float* __restrict__ cw6, const float* __restrict__ cb6,
    const float* __restrict__ deW, const float* __restrict__ deb,
    const float* __restrict__ rsW, const float* __restrict__ clW1,
    short* __restrict__ wB2s, short* __restrict__ wB3s,
    short* __restrict__ epre_s) {
  __shared__ float S[SLICE];
  short* Ssh = (short*)S;
  const int tid = threadIdx.x;
  const int sw = tid >> 6;          // wave in pair
  const int lane = tid & 63;
  const int quad = lane >> 4;
  const int l16 = lane & 15;
  const int unit = blockIdx.x;
  const float* xrow = x + (size_t)(unit >> 1) * 576 + (unit & 1) * 288;

  // ---- folded k0: swizzle-cast weights into MFMA-fragment order ----
  {
    int d = blockIdx.x * 128 + tid;
    if (d < 18 * 6 * 512) {
      int j = d & 7, ln = (d >> 3) & 63, t = d >> 9;
      int kf = t % 6, nf = t / 6;
      int n = nf * 16 + (ln & 15);
      int k = kf * 32 + (ln >> 4) * 8 + j;
      wB2s[d] = f2bf(rsW[n * 192 + k]);
    }
    if (d < 18 * 18 * 512) {
      int j = d & 7, ln = (d >> 3) & 63, t = d >> 9;
      int kf = t % 18, nt = t / 18;
      int n = nt * 16 + (ln & 15);
      int k = kf * 32 + (ln >> 4) * 8 + j;
      wB3s[d] = f2bf(clW1[n * 576 + k]);
    }
  }

  const float a0w0 = cw1[0], a0w1 = cw1[1], a0w2 = cw1[2], a0b = cb1[0];
  const float a1w0 = cw2[0], a1w1 = cw2[1], a1w2 = cw2[2], a1b = cb2[0];
  const float a2w0 = cw3[0], a2w1 = cw3[1], a2w2 = cw3[2], a2b = cb3[0];
  const float b0w0 = cw4[0], b0w1 = cw4[1], b0w2 = cw4[2], b0b = cb4[0];
  const float b1w0 = cw5[0], b1w1 = cw5[1], b1w2 = cw5[2], b1b = cb5[0];
  const float b2w0 = cw6[0], b2w1 = cw6[1], b2w2 = cw6[2], b2b = cb6[0];

  for (int t4 = tid; t4 < 72; t4 += 128)
    *(float4*)&S[O_CIN + 4 * t4] = ((const float4*)xrow)[t4];
  if (tid < 8) S[576 + 98 * (tid >> 1) + (tid & 1) * 97] = 0.f;
  __syncthreads();

  // stage-1 convs
  for (int t = tid; t < SEG; t += 128) {
    bool g1 = t >= 96, g2 = t >= 192;
    float wa = g2 ? a2w0 : (g1 ? a1w0 : a0w0);
    float wb = g2 ? a2w1 : (g1 ? a1w1 : a0w1);
    float wc = g2 ? a2w2 : (g1 ? a1w2 : a0w2);
    float bb = g2 ? a2b  : (g1 ? a1b  : a0b);
    int p = t - (g2 ? 192 : (g1 ? 96 : 0));
    float l = p > 0 ? S[O_CIN + t - 1] : 0.f;
    float m = S[O_CIN + t];
    float r = p < FLn - 1 ? S[O_CIN + t + 1] : 0.f;
    S[O_ST1 + t] = lrelu(fmaf(wa, l, fmaf(wb, m, fmaf(wc, r, bb))));
  }
  __syncthreads();
  // stage-2 convs -> aPp/aNp, xpP/xnP, bert
  for (int t = tid; t < SEG; t += 128) {
    bool g1 = t >= 96, g2 = t >= 192;
    float wa = g2 ? b2w0 : (g1 ? b1w0 : b0w0);
    float wb = g2 ? b2w1 : (g1 ? b1w1 : b0w1);
    float wc = g2 ? b2w2 : (g1 ? b1w2 : b0w2);
    float bb = g2 ? b2b  : (g1 ? b1b  : b0b);
    int p = t - (g2 ? 192 : (g1 ? 96 : 0));
    float l = p > 0 ? S[O_ST1 + t - 1] : 0.f;
    float m = S[O_ST1 + t];
    float r = p < FLn - 1 ? S[O_ST1 + t + 1] : 0.f;
    float v = lrelu(fmaf(wa, l, fmaf(wb, m, fmaf(wc, r, bb))));
    if (!g1) {
      S[O_APP + 1 + p] = fmaxf(v, 0.1f * v);
      S[O_ANP + 1 + p] = fminf(v, 0.1f * v);
    } else if (!g2) {
      S[O_XPP + 1 + p] = fmaxf(v, 0.f);
      S[O_XNP + 1 + p] = fminf(v, 0.f);
    } else {
      S[O_BERT + p] = v;
    }
  }
  __syncthreads();

  // wave0: per-sample 3x3 kernel (wker); wave1: A-matrix build (concurrent)
  if (sw == 0) {
    if (quad < 3) {
      float bv[6];
#pragma unroll
      for (int k = 0; k < 6; ++k) bv[k] = S[O_BERT + l16 + 16 * k];
#pragma unroll
      for (int oi = 0; oi < 3; ++oi) {
        int o = quad * 3 + oi;
        float p = 0.f;
#pragma unroll
        for (int k = 0; k < 6; ++k) p = fmaf(bv[k], deW[o * 96 + l16 + 16 * k], p);
        p += __shfl_xor(p, 1, 16);
        p += __shfl_xor(p, 2, 16);
        p += __shfl_xor(p, 4, 16);
        p += __shfl_xor(p, 8, 16);
        if (l16 == 0) S[O_WKER + o] = lrelu(p + deb[o]);
      }
    }
  } else {
    for (int m = lane; m < 96; m += 64) {
      short8 a;
      a[0] = f2bf(S[O_APP + m]);
      a[1] = f2bf(S[O_APP + m + 1]);
      a[2] = f2bf(S[O_APP + m + 2]);
      a[3] = f2bf(S[O_ANP + m]);
      a[4] = f2bf(S[O_ANP + m + 1]);
      a[5] = f2bf(S[O_ANP + m + 2]);
      a[6] = 0; a[7] = 0;
      *(short8*)&Ssh[2 * O_ABF + m * 8] = a;
    }
  }
  __syncthreads();

  // B-matrix build, 0.25-scaled (4-quad replication sums back to 1x)
  {
    float w9[9];
#pragma unroll
    for (int q = 0; q < 9; ++q) w9[q] = 0.25f * S[O_WKER + q];
    for (int t = tid; t < 96; t += 128) {
      float xp0 = S[O_XPP + t], xp1 = S[O_XPP + t + 1], xp2 = S[O_XPP + t + 2];
      float xn0 = S[O_XNP + t], xn1 = S[O_XNP + t + 1], xn2 = S[O_XNP + t + 2];
      short8 b;
#pragma unroll
      for (int d = 0; d < 3; ++d) {
        float cp = fmaf(w9[3 * d], xp0, fmaf(w9[3 * d + 1], xp1, w9[3 * d + 2] * xp2));
        float cn = fmaf(w9[3 * d], xn0, fmaf(w9[3 * d + 1], xn1, w9[3 * d + 2] * xn2));
        b[d] = f2bf(cp);
        b[3 + d] = f2bf(cn);
      }
      b[6] = 0; b[7] = 0;
      *(short8*)&Ssh[2 * O_BBF + t * 8] = b;
    }
  }
  __syncthreads();

  // field: each wave handles s-tiles {3*sw .. 3*sw+2}
  short8 aF[6];
#pragma unroll
  for (int mt = 0; mt < 6; ++mt)
    aF[mt] = *(const short8*)&Ssh[2 * O_ABF + (mt * 16 + l16) * 8];

  v2f rp2[6][2];
#pragma unroll
  for (int mt = 0; mt < 6; ++mt) {
    rp2[mt][0] = (v2f){0.f, 0.f};
    rp2[mt][1] = (v2f){0.f, 0.f};
  }
  float cs[3];

#pragma unroll
  for (int si = 0; si < 3; ++si) {
    const int s = 3 * sw + si;
    short8 bF = *(const short8*)&Ssh[2 * O_BBF + (s * 16 + l16) * 8];
    floatx4 accv[6];
#pragma unroll
    for (int mt = 0; mt < 6; ++mt)
      accv[mt] = __builtin_amdgcn_mfma_f32_16x16x32_bf16(
          aF[mt], bF, (floatx4){0.f, 0.f, 0.f, 0.f}, 0, 0, 0);
    v2f csl = (v2f){0.f, 0.f};
#pragma unroll
    for (int mt = 0; mt < 6; ++mt) {
      v2f lo = (v2f){accv[mt][0], accv[mt][1]};
      v2f hi = (v2f){accv[mt][2], accv[mt][3]};
      v2f tl = 0.1f * lo;
      v2f th = 0.1f * hi;
      v2f fl, fh;
      fl.x = fmaxf(lo.x, tl.x); fl.y = fmaxf(lo.y, tl.y);
      fh.x = fmaxf(hi.x, th.x); fh.y = fmaxf(hi.y, th.y);
      rp2[mt][0] += fl;
      rp2[mt][1] += fh;
      csl += fl + fh;
    }
    cs[si] = csl.x + csl.y;
  }
  __syncthreads();   // ABF/BBF fully consumed by both waves before RP overlay

  // row partials -> per-wave RP region
#pragma unroll
  for (int mt = 0; mt < 6; ++mt)
    *(float4*)&S[O_RP + sw * RPREG + (quad * 6 + mt) * 68 + l16 * 4] =
        make_float4(rp2[mt][0].x, rp2[mt][0].y, rp2[mt][1].x, rp2[mt][1].y);
  __syncthreads();

  // ---- swizzled epre writes: dst = (g*6+kf)*512 + (q*16 + (unit&15))*8 + j
  const int g = unit >> 4;
  const int u15 = unit & 15;
  short* eb = epre_s + (size_t)g * 6 * 512;
  // row means (value at kidx = i): sum both RP regions, 16 lanes each
  for (int i = tid; i < 96; i += 128) {
    int gg = ((i >> 2) & 3) * 6 + (i >> 4);
    int r = i & 3;
    float s = 0.f;
#pragma unroll
    for (int l = 0; l < 16; ++l)
      s += S[O_RP + gg * 68 + l * 4 + r] + S[O_RP + RPREG + gg * 68 + l * 4 + r];
    int kf = i >> 5, rem = i & 31, q = rem >> 3, j = rem & 7;
    eb[kf * 512 + (q * 16 + u15) * 8 + j] = f2bf(s * (1.f / FLn));
  }
  // col means: wave sw owns s = 3*sw+si (value at kidx = 96 + s*16 + l16)
#pragma unroll
  for (int si = 0; si < 3; ++si) {
    float v = cs[si];
    v += __shfl_xor(v, 16, 64);
    v += __shfl_xor(v, 32, 64);
    if (quad == 0) {
      int kidx = 96 + (3 * sw + si) * 16 + l16;
      int kf = kidx >> 5, rem = kidx & 31, q = rem >> 3, j = rem & 7;
      eb[kf * 512 + (q * 16 + u15) * 8 + j] = f2bf(v * (1.f / FLn));
    }
  }
}

// ---------------- K6: fused tail, fragment-contiguous loads (R9 proven) -----
__global__ __launch_bounds__(512) void k6_fused_tail(
    const short* __restrict__ epre_s, const short* __restrict__ wB2s,
    const short* __restrict__ wB3s, const float* __restrict__ x,
    const float* __restrict__ rsb, const float* __restrict__ rsg,
    const float* __restrict__ rsbe, const float* __restrict__ rsm,
    const float* __restrict__ rsv,
    const float* __restrict__ clb1, const float* __restrict__ clg,
    const float* __restrict__ clbe, const float* __restrict__ clm,
    const float* __restrict__ clv,
    const float* __restrict__ clW2, const float* __restrict__ clb2,
    float* __restrict__ out) {
  __shared__ short ceT[16 * 584]; // 18.7 KB
  __shared__ float scr[8 * 32];
  const int tid = threadIdx.x;
  const int w = tid >> 6;
  const int lane = tid & 63;
  const int quad = lane >> 4;
  const int l16 = lane & 15;
  const int s0 = blockIdx.x * 16;

  // ---- phase A ----
  const int mt = w & 1;
  const int ng = w >> 1;  // 0..3
  short8 aF[6];
  {
    const short* arow = epre_s + (size_t)(blockIdx.x * 2 + mt) * 6 * 512 + lane * 8;
#pragma unroll
    for (int kf = 0; kf < 6; ++kf) aF[kf] = *(const short8*)(arow + kf * 512);
  }

  for (int nf = ng; nf < 18; nf += 4) {
    const short* brow = wB2s + (size_t)nf * 6 * 512 + lane * 8;
    floatx4 acc = (floatx4){0.f, 0.f, 0.f, 0.f};
#pragma unroll
    for (int kf = 0; kf < 6; ++kf) {
      short8 bF = *(const short8*)(brow + kf * 512);
      acc = __builtin_amdgcn_mfma_f32_16x16x32_bf16(aF[kf], bF, acc, 0, 0, 0);
    }
    const int n = nf * 16 + l16;
    const float sc = rsg[n] * rsqrtf(rsv[n] + EPS_BN);
    const float vb = rsb[n], mu = rsm[n], vbe = rsbe[n];
#pragma unroll
    for (int r = 0; r < 4; ++r) {
      int um = mt * 16 + quad * 4 + r;   // unit-in-block 0..31
      int trow = um >> 1;                // sample 0..15
      int cc = (um & 1) * 288 + n;       // col 0..575
      float y = acc[r] + vb;
      float o = (y - mu) * sc + vbe;
      float e = lrelu(o) + x[(size_t)(s0 + trow) * 576 + cc];
      ceT[trow * 584 + cc] = f2bf(e);
    }
  }
  __syncthreads();

  // ---- phase B (+ cl2 fold) ----
  float p0[4], p1[4];
#pragma unroll
  for (int r = 0; r < 4; ++r) { p0[r] = 0.f; p1[r] = 0.f; }

  for (int nt = w; nt < 18; nt += 8) {
    const short* brow = wB3s + (size_t)nt * 18 * 512 + lane * 8;
    floatx4 acc = (floatx4){0.f, 0.f, 0.f, 0.f};
#pragma unroll
    for (int kf = 0; kf < 18; ++kf) {
      short8 cF = *(const short8*)&ceT[l16 * 584 + kf * 32 + quad * 8];
      short8 bF = *(const short8*)(brow + kf * 512);
      acc = __builtin_amdgcn_mfma_f32_16x16x32_bf16(cF, bF, acc, 0, 0, 0);
    }
    const int n = nt * 16 + l16;
    const float sc = clg[n] * rsqrtf(clv[n] + EPS_BN);
    const float vb = clb1[n], mu = clm[n], vbe = clbe[n];
    const float w2a = clW2[n], w2b = clW2[288 + n];
#pragma unroll
    for (int r = 0; r < 4; ++r) {
      float y = acc[r] + vb;
      float hh = fmaxf((y - mu) * sc + vbe, 0.f);
      p0[r] = fmaf(hh, w2a, p0[r]);
      p1[r] = fmaf(hh, w2b, p1[r]);
    }
  }
#pragma unroll
  for (int r = 0; r < 4; ++r) {
#pragma unroll
    for (int off = 1; off < 16; off <<= 1) {
      p0[r] += __shfl_xor(p0[r], off, 64);
      p1[r] += __shfl_xor(p1[r], off, 64);
    }
  }
  if (l16 == 0) {
#pragma unroll
    for (int r = 0; r < 4; ++r) {
      scr[w * 32 + (quad * 4 + r) * 2 + 0] = p0[r];
      scr[w * 32 + (quad * 4 + r) * 2 + 1] = p1[r];
    }
  }
  __syncthreads();
  if (tid < 32) {
    int row = tid >> 1, o = tid & 1;
    float s = 0.f;
#pragma unroll
    for (int g = 0; g < 8; ++g) s += scr[g * 32 + row * 2 + o];
    out[(size_t)(s0 + row) * 2 + o] = s + clb2[o];
  }
}

extern "C" void kernel_launch(void* const* d_in, const int* in_sizes, int n_in,
                              void* d_out, int out_size, void* d_ws, size_t ws_size,
                              hipStream_t stream) {
  const float* x   = (const float*)d_in[0];
  const float* cw1 = (const float*)d_in[1];  const float* cb1 = (const float*)d_in[2];
  const float* cw2 = (const float*)d_in[3];  const float* cb2 = (const float*)d_in[4];
  const float* cw3 = (const float*)d_in[5];  const float* cb3 = (const float*)d_in[6];
  const float* cw4 = (const float*)d_in[7];  const float* cb4 = (const float*)d_in[8];
  const float* cw5 = (const float*)d_in[9];  const float* cb5 = (const float*)d_in[10];
  const float* cw6 = (const float*)d_in[11]; const float* cb6 = (const float*)d_in[12];
  const float* deW = (const float*)d_in[13]; const float* deb = (const float*)d_in[14];
  const float* rsW = (const float*)d_in[15]; const float* rsb = (const float*)d_in[16];
  const float* rsg = (const float*)d_in[17]; const float* rsbe = (const float*)d_in[18];
  const float* rsm = (const float*)d_in[19]; const float* rsv = (const float*)d_in[20];
  const float* clW1 = (const float*)d_in[21]; const float* clb1 = (const float*)d_in[22];
  const float* clg = (const float*)d_in[23]; const float* clbe = (const float*)d_in[24];
  const float* clm = (const float*)d_in[25]; const float* clv = (const float*)d_in[26];
  const float* clW2 = (const float*)d_in[27]; const float* clb2 = (const float*)d_in[28];

  short* ws     = (short*)d_ws;
  short* epre_s = ws;                         // 16384*192 bf16 (fragment order)
  short* wB2s   = ws + 16384 * 192;           // 18*6*512 bf16
  short* wB3s   = wB2s + 18 * 6 * 512;        // 18*18*512 bf16

  hipLaunchKernelGGL(k1_persample, dim3(16384), dim3(128), 0, stream, x,
                     cw1, cb1, cw2, cb2, cw3, cb3, cw4, cb4, cw5, cb5, cw6, cb6,
                     deW, deb, rsW, clW1, wB2s, wB3s, epre_s);
  hipLaunchKernelGGL(k6_fused_tail, dim3(512), dim3(512), 0, stream,
                     epre_s, wB2s, wB3s, x,
                     rsb, rsg, rsbe, rsm, rsv,
                     clb1, clg, clbe, clm, clv,
                     clW2, clb2, (float*)d_out);
}